// Round 1
// baseline (713.211 us; speedup 1.0000x reference)
//
#include <hip/hip_runtime.h>
#include <hip/hip_bf16.h>

#define S_LEN 2048
#define HID   4096
#define NH    32
#define NKV   8
#define HD    128
#define QKV_N 6144
#define KDIM  4096

typedef __attribute__((ext_vector_type(8))) short short8;
typedef __attribute__((ext_vector_type(4))) float floatx4;

__device__ inline unsigned short f2bu(float f) {
  __hip_bfloat16 b = __float2bfloat16(f);
  return *reinterpret_cast<unsigned short*>(&b);
}
__device__ inline void store_c(float* p, float v) { *p = v; }
__device__ inline void store_c(__hip_bfloat16* p, float v) { *p = __float2bfloat16(v); }

// ---------------- fp32 -> bf16 convert ----------------
struct bf16x4 { __hip_bfloat16 a, b, c, d; };
__global__ void cvt_f32_bf16(const float* __restrict__ src, __hip_bfloat16* __restrict__ dst, int n4) {
  int i = blockIdx.x * blockDim.x + threadIdx.x;
  if (i < n4) {
    float4 v = ((const float4*)src)[i];
    bf16x4 o = { __float2bfloat16(v.x), __float2bfloat16(v.y),
                 __float2bfloat16(v.z), __float2bfloat16(v.w) };
    ((bf16x4*)dst)[i] = o;
  }
}

// ---------------- NT bf16 GEMM: C[M][N] = sum_k A[m][k]*B[n][k] ----------------
template <typename CT>
__global__ __launch_bounds__(256, 2) void gemm_nt(const __hip_bfloat16* __restrict__ A,
                                                  const __hip_bfloat16* __restrict__ B,
                                                  CT* __restrict__ C, int M, int N, int K) {
  __shared__ __align__(16) unsigned short As[128 * 32];
  __shared__ __align__(16) unsigned short Bs[128 * 32];
  const int tid  = threadIdx.x;
  const int bm   = blockIdx.y * 128;
  const int bn   = blockIdx.x * 128;
  const int wave = tid >> 6;
  const int lane = tid & 63;
  const int ww   = (wave >> 1) * 64;   // wave row offset in C tile
  const int wc   = (wave & 1) * 64;    // wave col offset
  const int l15  = lane & 15;
  const int quad = lane >> 4;

  const unsigned short* Au = (const unsigned short*)A;
  const unsigned short* Bu = (const unsigned short*)B;

  floatx4 acc[4][4] = {};

  const int c0 = tid, c1 = tid + 256;
  const int ar0 = c0 >> 2, ac0 = (c0 & 3) * 8;
  const int ar1 = c1 >> 2, ac1 = (c1 & 3) * 8;

  for (int k0 = 0; k0 < K; k0 += 32) {
    short8 a0 = *(const short8*)(Au + (size_t)(bm + ar0) * K + k0 + ac0);
    short8 a1 = *(const short8*)(Au + (size_t)(bm + ar1) * K + k0 + ac1);
    short8 b0 = *(const short8*)(Bu + (size_t)(bn + ar0) * K + k0 + ac0);
    short8 b1 = *(const short8*)(Bu + (size_t)(bn + ar1) * K + k0 + ac1);
    __syncthreads();
    *(short8*)&As[ar0 * 32 + ac0] = a0;
    *(short8*)&As[ar1 * 32 + ac1] = a1;
    *(short8*)&Bs[ar0 * 32 + ac0] = b0;
    *(short8*)&Bs[ar1 * 32 + ac1] = b1;
    __syncthreads();
    short8 af[4], bf[4];
#pragma unroll
    for (int i = 0; i < 4; ++i) {
      af[i] = *(const short8*)&As[(ww + i * 16 + l15) * 32 + quad * 8];
      bf[i] = *(const short8*)&Bs[(wc + i * 16 + l15) * 32 + quad * 8];
    }
#pragma unroll
    for (int mi = 0; mi < 4; ++mi)
#pragma unroll
      for (int ni = 0; ni < 4; ++ni)
        acc[mi][ni] = __builtin_amdgcn_mfma_f32_16x16x32_bf16(af[mi], bf[ni], acc[mi][ni], 0, 0, 0);
  }
#pragma unroll
  for (int mi = 0; mi < 4; ++mi)
#pragma unroll
    for (int ni = 0; ni < 4; ++ni)
#pragma unroll
      for (int r = 0; r < 4; ++r) {
        int row = bm + ww + mi * 16 + quad * 4 + r;  // C/D: row=(lane>>4)*4+reg
        int col = bn + wc + ni * 16 + l15;           //      col=lane&15
        store_c(&C[(size_t)row * N + col], acc[mi][ni][r]);
      }
}

// ---------------- RoPE for q,k -> head-major layouts ----------------
__global__ void rope_qk(const __hip_bfloat16* __restrict__ QKV,
                        const float* __restrict__ cosp, const float* __restrict__ sinp,
                        __hip_bfloat16* __restrict__ Qh, __hip_bfloat16* __restrict__ Kh) {
  int s = blockIdx.y;
  int col = blockIdx.x * 256 + threadIdx.x;  // 0..5119 (q then k region)
  if (col >= 5120) return;
  const size_t base = (size_t)s * QKV_N;
  float x = __bfloat162float(QKV[base + col]);
  int dd = col & 127;
  float val;
  if (dd < 64) {
    float xp = __bfloat162float(QKV[base + col + 64]);
    val = x * cosp[s * 64 + dd] - xp * sinp[s * 64 + dd];
  } else {
    int f = dd - 64;
    float xp = __bfloat162float(QKV[base + col - 64]);
    val = x * cosp[s * 64 + f] + xp * sinp[s * 64 + f];
  }
  if (col < HID) {
    int h = col >> 7;
    Qh[((size_t)h * S_LEN + s) * HD + dd] = __float2bfloat16(val);
  } else {
    int h = (col - HID) >> 7;
    Kh[((size_t)h * S_LEN + s) * HD + dd] = __float2bfloat16(val);
  }
}

// ---------------- V transpose: QKV[s][5120+h*128+d] -> Vt[h][d][s] ----------------
__global__ void v_transpose(const __hip_bfloat16* __restrict__ QKV, __hip_bfloat16* __restrict__ Vt) {
  __shared__ unsigned short tile[64][130];
  int h = blockIdx.y;
  int s0 = blockIdx.x * 64;
  int t = threadIdx.x;
  const unsigned short* src = (const unsigned short*)QKV;
#pragma unroll
  for (int i = 0; i < 32; ++i) {
    int flat = i * 256 + t;
    int r = flat >> 7, c = flat & 127;
    tile[r][c] = src[(size_t)(s0 + r) * QKV_N + 5120 + h * 128 + c];
  }
  __syncthreads();
  unsigned short* dst = (unsigned short*)Vt;
#pragma unroll
  for (int i = 0; i < 8; ++i) {
    int g = i * 256 + t;
    int d = g >> 4, j4 = (g & 15) * 4;
    ushort4 o;
    o.x = tile[j4][d]; o.y = tile[j4 + 1][d]; o.z = tile[j4 + 2][d]; o.w = tile[j4 + 3][d];
    *(ushort4*)&dst[((size_t)h * HD + d) * S_LEN + s0 + j4] = o;
  }
}

// ---------------- flash attention (per-wave, causal, GQA h%8) ----------------
__global__ __launch_bounds__(256, 2) void attn(const __hip_bfloat16* __restrict__ Qh,
                                               const __hip_bfloat16* __restrict__ Kh,
                                               const __hip_bfloat16* __restrict__ Vt,
                                               __hip_bfloat16* __restrict__ AO) {
  __shared__ __align__(16) unsigned short P[4][2][16][32];
  const int h = blockIdx.y;
  const int hk = h & 7;                    // jnp.tile => kv head = h % NKV
  const int wave = threadIdx.x >> 6;
  const int lane = threadIdx.x & 63;
  const int l15 = lane & 15, quad = lane >> 4;
  const int q0 = blockIdx.x * 128 + wave * 32;   // this wave's 32 q rows
  const unsigned short* Qu = (const unsigned short*)Qh + (size_t)h * S_LEN * HD;
  const unsigned short* Ku = (const unsigned short*)Kh + (size_t)hk * S_LEN * HD;
  const unsigned short* Vu = (const unsigned short*)Vt + (size_t)hk * HD * S_LEN;

  short8 qf[2][4];
#pragma unroll
  for (int mt = 0; mt < 2; ++mt)
#pragma unroll
    for (int kd = 0; kd < 4; ++kd)
      qf[mt][kd] = *(const short8*)(Qu + (size_t)(q0 + mt * 16 + l15) * HD + kd * 32 + quad * 8);

  floatx4 o[2][8] = {};
  float mstate[2][4], lsum[2][4];
#pragma unroll
  for (int mt = 0; mt < 2; ++mt)
#pragma unroll
    for (int r = 0; r < 4; ++r) { mstate[mt][r] = -1e30f; lsum[mt][r] = 0.f; }

  const float scale = 0.08838834764831845f;

  for (int j0 = 0; j0 < q0 + 32; j0 += 32) {
    short8 kf[2][4];
#pragma unroll
    for (int nt = 0; nt < 2; ++nt)
#pragma unroll
      for (int kd = 0; kd < 4; ++kd)
        kf[nt][kd] = *(const short8*)(Ku + (size_t)(j0 + nt * 16 + l15) * HD + kd * 32 + quad * 8);
    floatx4 sc[2][2] = {};
#pragma unroll
    for (int mt = 0; mt < 2; ++mt)
#pragma unroll
      for (int nt = 0; nt < 2; ++nt)
#pragma unroll
        for (int kd = 0; kd < 4; ++kd)
          sc[mt][nt] = __builtin_amdgcn_mfma_f32_16x16x32_bf16(qf[mt][kd], kf[nt][kd], sc[mt][nt], 0, 0, 0);

#pragma unroll
    for (int mt = 0; mt < 2; ++mt) {
      float p0v[4], p1v[4], mnew[4];
#pragma unroll
      for (int r = 0; r < 4; ++r) {
        int row = q0 + mt * 16 + quad * 4 + r;
        float v0 = sc[mt][0][r] * scale;
        float v1 = sc[mt][1][r] * scale;
        if (j0 + l15 > row) v0 = -1e30f;
        if (j0 + 16 + l15 > row) v1 = -1e30f;
        p0v[r] = v0; p1v[r] = v1;
        float vm = fmaxf(v0, v1);
        vm = fmaxf(vm, __shfl_xor(vm, 1));
        vm = fmaxf(vm, __shfl_xor(vm, 2));
        vm = fmaxf(vm, __shfl_xor(vm, 4));
        vm = fmaxf(vm, __shfl_xor(vm, 8));
        mnew[r] = fmaxf(mstate[mt][r], vm);
      }
#pragma unroll
      for (int r = 0; r < 4; ++r) {
        float alpha = __expf(mstate[mt][r] - mnew[r]);
        float p0 = __expf(p0v[r] - mnew[r]);
        float p1 = __expf(p1v[r] - mnew[r]);
        float ps = p0 + p1;
        ps += __shfl_xor(ps, 1);
        ps += __shfl_xor(ps, 2);
        ps += __shfl_xor(ps, 4);
        ps += __shfl_xor(ps, 8);
        lsum[mt][r] = lsum[mt][r] * alpha + ps;
        mstate[mt][r] = mnew[r];
#pragma unroll
        for (int t = 0; t < 8; ++t) o[mt][t][r] *= alpha;
        P[wave][mt][quad * 4 + r][l15] = f2bu(p0);
        P[wave][mt][quad * 4 + r][16 + l15] = f2bu(p1);
      }
    }
    asm volatile("s_waitcnt lgkmcnt(0)" ::: "memory");
    short8 pf[2];
    pf[0] = *(const short8*)&P[wave][0][l15][quad * 8];
    pf[1] = *(const short8*)&P[wave][1][l15][quad * 8];
    short8 vf[8];
#pragma unroll
    for (int t = 0; t < 8; ++t)
      vf[t] = *(const short8*)(Vu + (size_t)(t * 16 + l15) * S_LEN + j0 + quad * 8);
#pragma unroll
    for (int mt = 0; mt < 2; ++mt)
#pragma unroll
      for (int t = 0; t < 8; ++t)
        o[mt][t] = __builtin_amdgcn_mfma_f32_16x16x32_bf16(pf[mt], vf[t], o[mt][t], 0, 0, 0);
  }
#pragma unroll
  for (int mt = 0; mt < 2; ++mt)
#pragma unroll
    for (int t = 0; t < 8; ++t)
#pragma unroll
      for (int r = 0; r < 4; ++r) {
        int row = q0 + mt * 16 + quad * 4 + r;
        int d = t * 16 + l15;
        AO[(size_t)row * HID + h * HD + d] = __float2bfloat16(o[mt][t][r] / lsum[mt][r]);
      }
}

extern "C" void kernel_launch(void* const* d_in, const int* in_sizes, int n_in,
                              void* d_out, int out_size, void* d_ws, size_t ws_size,
                              hipStream_t stream) {
  const float* x    = (const float*)d_in[0];
  const float* wq   = (const float*)d_in[1];
  const float* wk   = (const float*)d_in[2];
  const float* wv   = (const float*)d_in[3];
  const float* wo   = (const float*)d_in[4];
  const float* cosp = (const float*)d_in[5];
  const float* sinp = (const float*)d_in[6];
  float* out = (float*)d_out;

  char* ws = (char*)d_ws;
  size_t off = 0;
  auto alloc = [&](size_t bytes) { char* p = ws + off; off += (bytes + 255) & ~255ull; return p; };
  __hip_bfloat16* Xb   = (__hip_bfloat16*)alloc((size_t)S_LEN * KDIM * 2);
  __hip_bfloat16* Wqkv = (__hip_bfloat16*)alloc((size_t)QKV_N * KDIM * 2);
  __hip_bfloat16* Wob  = (__hip_bfloat16*)alloc((size_t)HID * HID * 2);
  __hip_bfloat16* QKVb = (__hip_bfloat16*)alloc((size_t)S_LEN * QKV_N * 2);
  __hip_bfloat16* Qh   = (__hip_bfloat16*)alloc((size_t)NH * S_LEN * HD * 2);
  __hip_bfloat16* Kh   = (__hip_bfloat16*)alloc((size_t)NKV * S_LEN * HD * 2);
  __hip_bfloat16* Vt   = (__hip_bfloat16*)alloc((size_t)NKV * HD * S_LEN * 2);
  __hip_bfloat16* AO   = (__hip_bfloat16*)alloc((size_t)S_LEN * HID * 2);

  auto cvt = [&](const float* s, __hip_bfloat16* dpt, size_t n) {
    int n4 = (int)(n / 4);
    cvt_f32_bf16<<<dim3((n4 + 255) / 256), dim3(256), 0, stream>>>(s, dpt, n4);
  };
  cvt(x, Xb, (size_t)S_LEN * KDIM);
  cvt(wq, Wqkv, (size_t)HID * KDIM);
  cvt(wk, Wqkv + (size_t)HID * KDIM, (size_t)NKV * HD * KDIM);
  cvt(wv, Wqkv + (size_t)(HID + NKV * HD) * KDIM, (size_t)NKV * HD * KDIM);
  cvt(wo, Wob, (size_t)HID * HID);

  gemm_nt<__hip_bfloat16><<<dim3(QKV_N / 128, S_LEN / 128), dim3(256), 0, stream>>>(
      Xb, Wqkv, QKVb, S_LEN, QKV_N, KDIM);
  rope_qk<<<dim3(20, S_LEN), dim3(256), 0, stream>>>(QKVb, cosp, sinp, Qh, Kh);
  v_transpose<<<dim3(S_LEN / 64, NKV), dim3(256), 0, stream>>>(QKVb, Vt);
  attn<<<dim3(S_LEN / 128, NH), dim3(256), 0, stream>>>(Qh, Kh, Vt, AO);
  gemm_nt<float><<<dim3(HID / 128, S_LEN / 128), dim3(256), 0, stream>>>(
      AO, Wob, out, S_LEN, HID, KDIM);
}